// Round 8
// baseline (548.135 us; speedup 1.0000x reference)
//
#include <hip/hip_runtime.h>

typedef unsigned short u16;
typedef short bf16x8 __attribute__((ext_vector_type(8)));
typedef float f32x4 __attribute__((ext_vector_type(4)));

#define HN 16
#define SD 64
#define SEQ 2048
#define DM 1024
#define QSC 0.18033688f  // 0.125 * log2(e): softmax done in exp2 domain

__device__ __forceinline__ float bf2f(u16 h) {
  return __uint_as_float(((unsigned int)h) << 16);
}
__device__ __forceinline__ u16 f2bf(float f) {
  unsigned int x = __float_as_uint(f);
  x += 0x7fffu + ((x >> 16) & 1u);
  return (u16)(x >> 16);
}
__device__ __forceinline__ float geluf(float x) {
  return 0.5f * x * (1.0f + erff(x * 0.70710678118654752f));
}
__device__ __forceinline__ void load_lds16(const u16* g, u16* l) {
  __builtin_amdgcn_global_load_lds(
      (const __attribute__((address_space(1))) void*)g,
      (__attribute__((address_space(3))) void*)l, 16, 0, 0);
}

// ----------------------------------------------------- transpose tile (dev)
// in: K x N fp32 -> out: N x K bf16, one 64x64 tile at (tx,ty).
__device__ __forceinline__ void trans_tile(const float* __restrict__ in,
                                           u16* __restrict__ out, int K, int N,
                                           int tx, int ty, int tid,
                                           u16 (*T)[72]) {
  const int n0 = tx * 64, k0 = ty * 64;
#pragma unroll
  for (int it = 0; it < 2; ++it) {
    const int t = it * 256 + tid, r = t >> 3, c = (t & 7) * 8;
    const float* src = &in[(size_t)(k0 + r) * N + n0 + c];
    float4 d0 = *(const float4*)src;
    float4 d1 = *(const float4*)(src + 4);
    T[r][c + 0] = f2bf(d0.x);
    T[r][c + 1] = f2bf(d0.y);
    T[r][c + 2] = f2bf(d0.z);
    T[r][c + 3] = f2bf(d0.w);
    T[r][c + 4] = f2bf(d1.x);
    T[r][c + 5] = f2bf(d1.y);
    T[r][c + 6] = f2bf(d1.z);
    T[r][c + 7] = f2bf(d1.w);
  }
  __syncthreads();
#pragma unroll
  for (int it = 0; it < 2; ++it) {
    const int t = it * 256 + tid, r = t >> 3, c = (t & 7) * 8;
    uint4 d;
    u16* p = (u16*)&d;
#pragma unroll
    for (int j = 0; j < 8; ++j) p[j] = T[c + j][r];
    *(uint4*)&out[(size_t)(n0 + r) * K + k0 + c] = d;
  }
}

// ------------------------------------------------- prep1: 6 WT + mem f2b
__global__ __launch_bounds__(256) void prep1(
    const float* __restrict__ Wqkv, const float* __restrict__ Wo,
    const float* __restrict__ Wqc, const float* __restrict__ Wkc,
    const float* __restrict__ Wvc, const float* __restrict__ Wco,
    u16* __restrict__ Tqkv, u16* __restrict__ To, u16* __restrict__ Tqc,
    u16* __restrict__ Tkc, u16* __restrict__ Tvc, u16* __restrict__ Tco,
    const float* __restrict__ mem, u16* __restrict__ memb) {
  __shared__ u16 T[64][72];
  const int t = blockIdx.x, tid = threadIdx.x;
  if (t < 768) {  // W_qkv: (1024,3072): 48x16 tiles
    trans_tile(Wqkv, Tqkv, 1024, 3072, t % 48, t / 48, tid, T);
    return;
  }
  if (t < 2048) {  // 5 x (1024,1024): 256 tiles each
    const int u = t - 768, m = u >> 8, sub = u & 255;
    const float* in;
    u16* out;
    if (m == 0) { in = Wo; out = To; }
    else if (m == 1) { in = Wqc; out = Tqc; }
    else if (m == 2) { in = Wkc; out = Tkc; }
    else if (m == 3) { in = Wvc; out = Tvc; }
    else { in = Wco; out = Tco; }
    trans_tile(in, out, 1024, 1024, sub & 15, sub >> 4, tid, T);
    return;
  }
  // memory f2b: 131072 elems, 128 blocks
  const int i = ((t - 2048) * 256 + tid) * 4;
  float4 d = *(const float4*)&mem[i];
  uint2 o;
  u16* po = (u16*)&o;
  po[0] = f2bf(d.x);
  po[1] = f2bf(d.y);
  po[2] = f2bf(d.z);
  po[3] = f2bf(d.w);
  *(uint2*)&memb[i] = o;
}

// ------------------------------------------------- prep2: W1 + W2 transpose
__global__ __launch_bounds__(256) void prep2(const float* __restrict__ W1,
                                             const float* __restrict__ W2,
                                             u16* __restrict__ T1,
                                             u16* __restrict__ T2) {
  __shared__ u16 T[64][72];
  const int t = blockIdx.x, tid = threadIdx.x;
  if (t < 1024) {  // W1 (1024,4096): 64x16 tiles
    trans_tile(W1, T1, 1024, 4096, t & 63, t >> 6, tid, T);
  } else {  // W2 (4096,1024): 16x64 tiles
    const int u = t - 1024;
    trans_tile(W2, T2, 4096, 1024, u & 15, u >> 4, tid, T);
  }
}

// ---------------------------------------------------------------- layernorm
__global__ __launch_bounds__(256) void ln_kernel(
    const float* __restrict__ x, const float* __restrict__ g,
    const float* __restrict__ be, u16* __restrict__ y) {
  const int row = blockIdx.x, tid = threadIdx.x;
  const float* xr = x + (size_t)row * DM;
  float4 d = *(const float4*)&xr[tid * 4];
  float v[4] = {d.x, d.y, d.z, d.w};
  float s1 = 0.f, s2 = 0.f;
#pragma unroll
  for (int j = 0; j < 4; ++j) {
    s1 += v[j];
    s2 += v[j] * v[j];
  }
#pragma unroll
  for (int dd = 1; dd < 64; dd <<= 1) {
    s1 += __shfl_xor(s1, dd, 64);
    s2 += __shfl_xor(s2, dd, 64);
  }
  __shared__ float p1[4], p2[4];
  const int lane = tid & 63, wv = tid >> 6;
  if (lane == 0) {
    p1[wv] = s1;
    p2[wv] = s2;
  }
  __syncthreads();
  s1 = p1[0] + p1[1] + p1[2] + p1[3];
  s2 = p2[0] + p2[1] + p2[2] + p2[3];
  const float mu = s1 * (1.f / DM);
  const float rs = rsqrtf(fmaxf(s2 * (1.f / DM) - mu * mu, 0.f) + 1e-5f);
  float4 gg = *(const float4*)&g[tid * 4];
  float4 bb = *(const float4*)&be[tid * 4];
  const float gv[4] = {gg.x, gg.y, gg.z, gg.w};
  const float bv[4] = {bb.x, bb.y, bb.z, bb.w};
  uint2 o;
  u16* po = (u16*)&o;
#pragma unroll
  for (int j = 0; j < 4; ++j) po[j] = f2bf((v[j] - mu) * rs * gv[j] + bv[j]);
  *(uint2*)&y[(size_t)row * DM + tid * 4] = o;
}

// ---------------------------------------------------------------- GEMM
// C(M,N) = A(M,K)*Bt(N,K)^T + bias. A,Bt bf16; bias/resid fp32.
// Tile TM x 128, BK=64, XCD m-band swizzle, XOR-swizzled LDS layout.
// EPI: 0 plain->bf16, 1 +resid->fp32, 2 gelu->bf16,
//      3 qkv scatter WITH FUSED ROPE (q scaled by QSC; v transposed),
//      4 scaled scatter [B,H,SL,64], 5 scatter transposed [B,H,64,SL],
//      6 kc/vc pair: blockIdx.z=0 -> C0 as EPI4; z=1 -> Bt=C1,bias=resid,
//        output C2 as EPI5.
template <int EPI, int TM>
__global__ __launch_bounds__(256) void gemm_bt(
    const u16* __restrict__ A, const u16* __restrict__ Bt,
    const float* __restrict__ bias, const float* __restrict__ resid,
    void* __restrict__ C0, u16* __restrict__ C1, u16* __restrict__ C2, int M,
    int N, int K, int rpbl, float sc, const float* __restrict__ rcos,
    const float* __restrict__ rsin) {
  constexpr int MI = TM / 32;  // m-fragments per wave
  __shared__ __align__(16) u16 As[TM][64];
  __shared__ __align__(16) u16 Bs[128][64];
  const int tid = threadIdx.x;
  const int lane = tid & 63, wv = tid >> 6;
  const int l16 = lane & 15, quad = lane >> 4;

  if (EPI == 6 && blockIdx.z) {  // v-branch: swap weight/bias
    Bt = (const u16*)C1;
    bias = resid;
  }

  // XCD-aware m-band swizzle (n-fastest within band)
  int bx = blockIdx.x, by = blockIdx.y;
  const int gx = gridDim.x, gy = gridDim.y;
  if ((gy & 7) == 0) {
    const int f = by * gx + bx;
    const int c = f & 7, j = f >> 3;
    const int jm = j / gx;
    by = c * (gy >> 3) + jm;
    bx = j - jm * gx;
  }
  const int m0 = by * TM, n0 = bx * 128;
  const int wm = (wv >> 1) * (TM / 2), wn = (wv & 1) * 64;

  const int srow = lane >> 3;
  const int sblk = (lane & 7) ^ srow;
  const u16* ag[MI];
  const u16* bg[4];
  u16* la[MI];
  u16* lb[4];
#pragma unroll
  for (int i = 0; i < MI; ++i) {
    const int r0 = i * 32 + wv * 8;
    ag[i] = A + (size_t)(m0 + r0 + srow) * K + sblk * 8;
    la[i] = &As[r0][0] + lane * 8;
  }
#pragma unroll
  for (int i = 0; i < 4; ++i) {
    const int r0 = i * 32 + wv * 8;
    bg[i] = Bt + (size_t)(n0 + r0 + srow) * K + sblk * 8;
    lb[i] = &Bs[r0][0] + lane * 8;
  }

  f32x4 acc[MI][4] = {};

  for (int k0 = 0; k0 < K; k0 += 64) {
    __syncthreads();
#pragma unroll
    for (int i = 0; i < MI; ++i) load_lds16(ag[i] + k0, la[i]);
#pragma unroll
    for (int i = 0; i < 4; ++i) load_lds16(bg[i] + k0, lb[i]);
    __syncthreads();
#pragma unroll
    for (int kk = 0; kk < 2; ++kk) {
      bf16x8 af[MI], bfr[4];
#pragma unroll
      for (int mi = 0; mi < MI; ++mi) {
        const int row = wm + mi * 16 + l16;
        const int blk = (kk * 4 + quad) ^ (row & 7);
        af[mi] = *(const bf16x8*)&As[row][blk * 8];
      }
#pragma unroll
      for (int ni = 0; ni < 4; ++ni) {
        const int row = wn + ni * 16 + l16;
        const int blk = (kk * 4 + quad) ^ (row & 7);
        bfr[ni] = *(const bf16x8*)&Bs[row][blk * 8];
      }
#pragma unroll
      for (int mi = 0; mi < MI; ++mi)
#pragma unroll
        for (int ni = 0; ni < 4; ++ni)
          acc[mi][ni] = __builtin_amdgcn_mfma_f32_16x16x32_bf16(
              af[mi], bfr[ni], acc[mi][ni], 0, 0, 0);
    }
  }

  const int SL = 1 << rpbl;
#pragma unroll
  for (int mi = 0; mi < MI; ++mi) {
#pragma unroll
    for (int ni = 0; ni < 4; ++ni) {
#pragma unroll
      for (int r = 0; r < 4; ++r) {
        const int row = m0 + wm + mi * 16 + quad * 4 + r;
        const int col = n0 + wn + ni * 16 + l16;
        float vv = acc[mi][ni][r] + bias[col];
        if (EPI == 1) {
          vv += resid[(size_t)row * N + col];
          ((float*)C0)[(size_t)row * N + col] = vv;
        } else if (EPI == 2) {
          ((u16*)C0)[(size_t)row * N + col] = f2bf(geluf(vv));
        } else if (EPI == 3) {
          const float partner = __shfl_xor(vv, 1);
          const int which = col >> 10;
          const int nn = col & 1023;
          const int h = nn >> 6, hd = nn & 63;
          const int b = row >> rpbl;
          const int s = row & (SL - 1);
          if (which == 2) {  // V: transposed [B,H,64,SL]
            C2[(((size_t)b * HN + h) * SD + hd) * SL + s] = f2bf(vv);
          } else {  // q/k: fused RoPE
            const int p = hd >> 1;
            const float cv = rcos[s * 32 + p];
            const float sv2 = rsin[s * 32 + p];
            float o = (hd & 1) ? (partner * sv2 + vv * cv)
                               : (vv * cv - partner * sv2);
            if (which == 0) o *= QSC;
            u16* dst = (which == 0) ? (u16*)C0 : C1;
            dst[(((size_t)b * HN + h) * SL + s) * SD + hd] = f2bf(o);
          }
        } else if (EPI == 4) {
          vv *= sc;
          const int h = col >> 6, hd = col & 63;
          const int b = row >> rpbl;
          const int s = row & (SL - 1);
          ((u16*)C0)[(((size_t)b * HN + h) * SL + s) * SD + hd] = f2bf(vv);
        } else if (EPI == 5) {
          const int h = col >> 6, hd = col & 63;
          const int b = row >> rpbl;
          const int s = row & (SL - 1);
          ((u16*)C0)[(((size_t)b * HN + h) * SD + hd) * SL + s] = f2bf(vv);
        } else if (EPI == 6) {
          const int h = col >> 6, hd = col & 63;
          const int b = row >> rpbl;
          const int s = row & (SL - 1);
          if (blockIdx.z == 0)
            ((u16*)C0)[(((size_t)b * HN + h) * SL + s) * SD + hd] = f2bf(vv);
          else
            C2[(((size_t)b * HN + h) * SD + hd) * SL + s] = f2bf(vv);
        } else {
          ((u16*)C0)[(size_t)row * N + col] = f2bf(vv);
        }
      }
    }
  }
}

// ---------------------------------------------------------------- attention
// One q-tile per block, 512 thr. Wave-group A (waves 0-3) handles EVEN kv
// sub-tiles, group B (4-7) ODD, concurrently; fixed-max exp2 softmax makes
// partials additive -> merged via LDS at the end. 128 kv cols staged/round.
// q: [B,H,2048,64]; k: [B,H,kv,64]; vt: [B,H,64,kv]. out: [B,S,1024] bf16.
template <int CAUSAL>
__global__ __launch_bounds__(512, 4) void attn_kernel(
    const u16* __restrict__ q, const u16* __restrict__ k,
    const u16* __restrict__ vt, u16* __restrict__ out, int kv_len) {
  __shared__ u16 Qs[64][72];
  __shared__ u16 Ks[128][72];   // merge: fp32 O partial [64][68] overlay
  __shared__ u16 VTs[64][136];  // merge: fp32 l partial [64] overlay
  __shared__ u16 Ps[128][68];   // wave-private rows [wv*16, wv*16+16)
  const int tid = threadIdx.x;
  const int lane = tid & 63, wv = tid >> 6;  // wave 0..7
  const int t2 = wv >> 2, w4 = wv & 3;       // kv-parity group, q-strip
  const int l16 = lane & 15, quad = lane >> 4;
  const int qt = blockIdx.x, bh = blockIdx.y;
  const u16* qb = q + ((size_t)bh * SEQ + qt * 64) * SD;
  const u16* kb = k + (size_t)bh * kv_len * SD;
  const u16* vtb = vt + (size_t)bh * SD * kv_len;

  {  // stage Q (64x64): 1 x 16B per thread
    const int r = tid >> 3, c = (tid & 7) * 8;
    *(uint4*)&Qs[r][c] = *(const uint4*)&qb[(size_t)r * SD + c];
  }

  f32x4 o_acc[4] = {};
  float l_i[4] = {};

  const int nround =
      CAUSAL ? ((qt >> 1) + 1) : ((kv_len + 127) >> 7);
  const int kr = tid >> 2, kc4 = (tid & 3) * 16;
  const int vr = tid >> 3, vc16 = (tid & 7) * 16;

  for (int rd = 0; rd < nround; ++rd) {
    const int c0 = rd << 7;
    uint4 ka0 = {0, 0, 0, 0}, ka1 = {0, 0, 0, 0};
    uint4 va0 = {0, 0, 0, 0}, va1 = {0, 0, 0, 0};
    if (c0 + kr < kv_len) {
      ka0 = *(const uint4*)&kb[(size_t)(c0 + kr) * SD + kc4];
      ka1 = *(const uint4*)&kb[(size_t)(c0 + kr) * SD + kc4 + 8];
    }
    if (c0 + vc16 < kv_len) {
      va0 = *(const uint4*)&vtb[(size_t)vr * kv_len + c0 + vc16];
      va1 = *(const uint4*)&vtb[(size_t)vr * kv_len + c0 + vc16 + 8];
    }
    __syncthreads();
    *(uint4*)&Ks[kr][kc4] = ka0;
    *(uint4*)&Ks[kr][kc4 + 8] = ka1;
    *(uint4*)&VTs[vr][vc16] = va0;
    *(uint4*)&VTs[vr][vc16 + 8] = va1;
    __syncthreads();

    const int st = (rd << 1) + t2;
    const bool part = CAUSAL ? (st <= qt) : (st * 64 < kv_len);
    if (part) {
      f32x4 s_acc[4] = {};
#pragma unroll
      for (int kk = 0; kk < 64; kk += 32) {
        const bf16x8 aq = *(const bf16x8*)&Qs[w4 * 16 + l16][kk + quad * 8];
#pragma unroll
        for (int ni = 0; ni < 4; ++ni) {
          const bf16x8 bk =
              *(const bf16x8*)&Ks[t2 * 64 + ni * 16 + l16][kk + quad * 8];
          s_acc[ni] = __builtin_amdgcn_mfma_f32_16x16x32_bf16(aq, bk, s_acc[ni],
                                                              0, 0, 0);
        }
      }
      float rsum[4] = {0.f, 0.f, 0.f, 0.f};
      const bool dg = CAUSAL && (st == qt);
#pragma unroll
      for (int ni = 0; ni < 4; ++ni)
#pragma unroll
        for (int r = 0; r < 4; ++r) {
          float sv = s_acc[ni][r];
          if (dg && (ni * 16 + l16 > w4 * 16 + quad * 4 + r)) sv = -1e9f;
          const float pe = __builtin_amdgcn_exp2f(sv);
          rsum[r] += pe;
          Ps[wv * 16 + quad * 4 + r][ni * 16 + l16] =
              (u16)(__float_as_uint(pe) >> 16);
        }
#pragma unroll
      for (int r = 0; r < 4; ++r) {
#pragma unroll
        for (int dd = 1; dd < 16; dd <<= 1)
          rsum[r] += __shfl_xor(rsum[r], dd, 64);
        l_i[r] += rsum[r];
      }
#pragma unroll
      for (int kk = 0; kk < 64; kk += 32) {
        const bf16x8 ap = *(const bf16x8*)&Ps[wv * 16 + l16][kk + quad * 8];
#pragma unroll
        for (int ni = 0; ni < 4; ++ni) {
          const bf16x8 bv =
              *(const bf16x8*)&VTs[ni * 16 + l16][t2 * 64 + kk + quad * 8];
          o_acc[ni] = __builtin_amdgcn_mfma_f32_16x16x32_bf16(ap, bv, o_acc[ni],
                                                              0, 0, 0);
        }
      }
    }
  }

  // merge group B into group A via LDS (Ks/VTs are dead now)
  __syncthreads();
  float* Omb = (float*)&Ks[0][0];
  float* lbuf = (float*)&VTs[0][0];
  if (t2 == 1) {
#pragma unroll
    for (int r = 0; r < 4; ++r) {
      const int row = w4 * 16 + quad * 4 + r;
      if (l16 == 0) lbuf[row] = l_i[r];
#pragma unroll
      for (int ni = 0; ni < 4; ++ni)
        Omb[row * 68 + ni * 16 + l16] = o_acc[ni][r];
    }
  }
  __syncthreads();
  if (t2 == 0) {
    const int b = bh >> 4, h = bh & 15;
#pragma unroll
    for (int r = 0; r < 4; ++r) {
      const int row = w4 * 16 + quad * 4 + r;
      const float inv = 1.f / (l_i[r] + lbuf[row]);
      const int s = qt * 64 + row;
#pragma unroll
      for (int ni = 0; ni < 4; ++ni) {
        const float val = o_acc[ni][r] + Omb[row * 68 + ni * 16 + l16];
        out[((size_t)b * SEQ + s) * DM + h * SD + ni * 16 + l16] =
            f2bf(val * inv);
      }
    }
  }
}

// ---------------------------------------------------------------- launch
extern "C" void kernel_launch(void* const* d_in, const int* in_sizes, int n_in,
                              void* d_out, int out_size, void* d_ws,
                              size_t ws_size, hipStream_t stream) {
  (void)in_sizes;
  (void)n_in;
  (void)out_size;
  (void)ws_size;
  const float* tgt = (const float*)d_in[0];
  const float* mem = (const float*)d_in[1];
  const float* rc = (const float*)d_in[2];
  const float* rsn = (const float*)d_in[3];
  const float* W_qkv = (const float*)d_in[4];
  const float* b_qkv = (const float*)d_in[5];
  const float* W_o = (const float*)d_in[6];
  const float* b_o = (const float*)d_in[7];
  const float* Wq_c = (const float*)d_in[8];
  const float* bq_c = (const float*)d_in[9];
  const float* Wk_c = (const float*)d_in[10];
  const float* bk_c = (const float*)d_in[11];
  const float* Wv_c = (const float*)d_in[12];
  const float* bv_c = (const float*)d_in[13];
  const float* W_co = (const float*)d_in[14];
  const float* b_co = (const float*)d_in[15];
  const float* W1 = (const float*)d_in[16];
  const float* b1 = (const float*)d_in[17];
  const float* W2 = (const float*)d_in[18];
  const float* b2 = (const float*)d_in[19];
  const float* g1 = (const float*)d_in[20];
  const float* be1 = (const float*)d_in[21];
  const float* g2 = (const float*)d_in[22];
  const float* be2 = (const float*)d_in[23];
  const float* g3 = (const float*)d_in[24];
  const float* be3 = (const float*)d_in[25];

  // --- workspace layout (u16 elements), ~57 MB ---
  const size_t M1 = 1048576;
  u16* w = (u16*)d_ws;
  u16* WTqkv = w;          // 3M  } early-WT region: 8M u16, dead after W_co
  u16* WTo = w + 3 * M1;   // 1M  } projection; reused for WT1/WT2
  u16* WTqc = w + 4 * M1;  // 1M
  u16* WTkc = w + 5 * M1;  // 1M
  u16* WTvc = w + 6 * M1;  // 1M
  u16* WTco = w + 7 * M1;  // 1M
  u16* WT1 = w;            // 4M (aliases WTqkv+WTo, transposed late)
  u16* WT2 = w + 4 * M1;   // 4M (aliases WTqc..WTco, transposed late)
  u16* xb = w + 8 * M1;    // 4M
  u16* qb = w + 12 * M1;   // 4M
  u16* kb = w + 16 * M1;   // 4M
  u16* vbT = w + 20 * M1;  // 4M  V pre-transposed [B,H,64,2048]
  u16* at = w + 24 * M1;   // 4M
  u16* kc = w + 28 * M1;   // 128K [B,H,64,64]
  u16* vcT = kc + 131072;  // 128K [B,H,64,64] transposed
  u16* memb = vcT + 131072;  // 128K memory as bf16
  u16* ffh = qb;             // FFN hidden 16M u16: aliases dead qb..at
  float* res = (float*)d_out;  // fp32 residual stream lives in d_out

  dim3 blk(256), blk512(512);
  prep1<<<2176, blk, 0, stream>>>(W_qkv, W_o, Wq_c, Wk_c, Wv_c, W_co, WTqkv,
                                  WTo, WTqc, WTkc, WTvc, WTco, mem, memb);

  // --- self-attention block
  ln_kernel<<<4096, blk, 0, stream>>>(tgt, g1, be1, xb);
  gemm_bt<3, 128><<<dim3(24, 32), blk, 0, stream>>>(
      xb, WTqkv, b_qkv, nullptr, qb, kb, vbT, 4096, 3072, 1024, 11, 1.f, rc,
      rsn);
  attn_kernel<1><<<dim3(32, 32), blk512, 0, stream>>>(qb, kb, vbT, at, 2048);
  gemm_bt<1, 64><<<dim3(8, 64), blk, 0, stream>>>(at, WTo, b_o, tgt, res,
                                                  nullptr, nullptr, 4096, 1024,
                                                  1024, 0, 1.f, nullptr,
                                                  nullptr);
  // --- cross-attention block
  ln_kernel<<<4096, blk, 0, stream>>>(res, g2, be2, xb);
  gemm_bt<4, 64><<<dim3(8, 64), blk, 0, stream>>>(
      xb, WTqc, bq_c, nullptr, qb, nullptr, nullptr, 4096, 1024, 1024, 11, QSC,
      nullptr, nullptr);
  gemm_bt<6, 64><<<dim3(8, 2, 2), blk, 0, stream>>>(
      memb, WTkc, bk_c, bv_c, kc, WTvc, vcT, 128, 1024, 1024, 6, 1.f, nullptr,
      nullptr);
  attn_kernel<0><<<dim3(32, 32), blk512, 0, stream>>>(qb, kc, vcT, at, 64);
  gemm_bt<1, 64><<<dim3(8, 64), blk, 0, stream>>>(at, WTco, b_co, res, res,
                                                  nullptr, nullptr, 4096, 1024,
                                                  1024, 0, 1.f, nullptr,
                                                  nullptr);
  // --- FFN block (early WTs now dead; transpose W1/W2 into their region)
  prep2<<<2048, blk, 0, stream>>>(W1, W2, WT1, WT2);
  ln_kernel<<<4096, blk, 0, stream>>>(res, g3, be3, xb);
  gemm_bt<2, 128><<<dim3(32, 32), blk, 0, stream>>>(
      xb, WT1, b1, nullptr, ffh, nullptr, nullptr, 4096, 4096, 1024, 0, 1.f,
      nullptr, nullptr);
  gemm_bt<1, 64><<<dim3(8, 64), blk, 0, stream>>>(ffh, WT2, b2, res, res,
                                                  nullptr, nullptr, 4096, 1024,
                                                  4096, 0, 1.f, nullptr,
                                                  nullptr);
}

// Round 9
// 510.024 us; speedup vs baseline: 1.0747x; 1.0747x over previous
//
#include <hip/hip_runtime.h>

typedef unsigned short u16;
typedef short bf16x8 __attribute__((ext_vector_type(8)));
typedef float f32x4 __attribute__((ext_vector_type(4)));

#define HN 16
#define SD 64
#define SEQ 2048
#define DM 1024
#define QSC 0.18033688f  // 0.125 * log2(e): softmax done in exp2 domain

__device__ __forceinline__ float bf2f(u16 h) {
  return __uint_as_float(((unsigned int)h) << 16);
}
__device__ __forceinline__ u16 f2bf(float f) {
  unsigned int x = __float_as_uint(f);
  x += 0x7fffu + ((x >> 16) & 1u);
  return (u16)(x >> 16);
}
__device__ __forceinline__ float geluf(float x) {
  return 0.5f * x * (1.0f + erff(x * 0.70710678118654752f));
}
__device__ __forceinline__ void load_lds16(const u16* g, u16* l) {
  __builtin_amdgcn_global_load_lds(
      (const __attribute__((address_space(1))) void*)g,
      (__attribute__((address_space(3))) void*)l, 16, 0, 0);
}

// ----------------------------------------------------- transpose tile (dev)
// in: K x N fp32 -> out: N x K bf16, one 64x64 tile at (tx,ty).
__device__ __forceinline__ void trans_tile(const float* __restrict__ in,
                                           u16* __restrict__ out, int K, int N,
                                           int tx, int ty, int tid,
                                           u16 (*T)[72]) {
  const int n0 = tx * 64, k0 = ty * 64;
#pragma unroll
  for (int it = 0; it < 2; ++it) {
    const int t = it * 256 + tid, r = t >> 3, c = (t & 7) * 8;
    const float* src = &in[(size_t)(k0 + r) * N + n0 + c];
    float4 d0 = *(const float4*)src;
    float4 d1 = *(const float4*)(src + 4);
    T[r][c + 0] = f2bf(d0.x);
    T[r][c + 1] = f2bf(d0.y);
    T[r][c + 2] = f2bf(d0.z);
    T[r][c + 3] = f2bf(d0.w);
    T[r][c + 4] = f2bf(d1.x);
    T[r][c + 5] = f2bf(d1.y);
    T[r][c + 6] = f2bf(d1.z);
    T[r][c + 7] = f2bf(d1.w);
  }
  __syncthreads();
#pragma unroll
  for (int it = 0; it < 2; ++it) {
    const int t = it * 256 + tid, r = t >> 3, c = (t & 7) * 8;
    uint4 d;
    u16* p = (u16*)&d;
#pragma unroll
    for (int j = 0; j < 8; ++j) p[j] = T[c + j][r];
    *(uint4*)&out[(size_t)(n0 + r) * K + k0 + c] = d;
  }
}

// ------------------------------------------------- prep1: 6 WT + mem f2b
__global__ __launch_bounds__(256) void prep1(
    const float* __restrict__ Wqkv, const float* __restrict__ Wo,
    const float* __restrict__ Wqc, const float* __restrict__ Wkc,
    const float* __restrict__ Wvc, const float* __restrict__ Wco,
    u16* __restrict__ Tqkv, u16* __restrict__ To, u16* __restrict__ Tqc,
    u16* __restrict__ Tkc, u16* __restrict__ Tvc, u16* __restrict__ Tco,
    const float* __restrict__ mem, u16* __restrict__ memb) {
  __shared__ u16 T[64][72];
  const int t = blockIdx.x, tid = threadIdx.x;
  if (t < 768) {  // W_qkv: (1024,3072): 48x16 tiles
    trans_tile(Wqkv, Tqkv, 1024, 3072, t % 48, t / 48, tid, T);
    return;
  }
  if (t < 2048) {  // 5 x (1024,1024): 256 tiles each
    const int u = t - 768, m = u >> 8, sub = u & 255;
    const float* in;
    u16* out;
    if (m == 0) { in = Wo; out = To; }
    else if (m == 1) { in = Wqc; out = Tqc; }
    else if (m == 2) { in = Wkc; out = Tkc; }
    else if (m == 3) { in = Wvc; out = Tvc; }
    else { in = Wco; out = Tco; }
    trans_tile(in, out, 1024, 1024, sub & 15, sub >> 4, tid, T);
    return;
  }
  // memory f2b: 131072 elems, 128 blocks
  const int i = ((t - 2048) * 256 + tid) * 4;
  float4 d = *(const float4*)&mem[i];
  uint2 o;
  u16* po = (u16*)&o;
  po[0] = f2bf(d.x);
  po[1] = f2bf(d.y);
  po[2] = f2bf(d.z);
  po[3] = f2bf(d.w);
  *(uint2*)&memb[i] = o;
}

// ------------------------------------------------- prep2: W1 + W2 transpose
__global__ __launch_bounds__(256) void prep2(const float* __restrict__ W1,
                                             const float* __restrict__ W2,
                                             u16* __restrict__ T1,
                                             u16* __restrict__ T2) {
  __shared__ u16 T[64][72];
  const int t = blockIdx.x, tid = threadIdx.x;
  if (t < 1024) {  // W1 (1024,4096): 64x16 tiles
    trans_tile(W1, T1, 1024, 4096, t & 63, t >> 6, tid, T);
  } else {  // W2 (4096,1024): 16x64 tiles
    const int u = t - 1024;
    trans_tile(W2, T2, 4096, 1024, u & 15, u >> 4, tid, T);
  }
}

// ---------------------------------------------------------------- layernorm
__global__ __launch_bounds__(256) void ln_kernel(
    const float* __restrict__ x, const float* __restrict__ g,
    const float* __restrict__ be, u16* __restrict__ y) {
  const int row = blockIdx.x, tid = threadIdx.x;
  const float* xr = x + (size_t)row * DM;
  float4 d = *(const float4*)&xr[tid * 4];
  float v[4] = {d.x, d.y, d.z, d.w};
  float s1 = 0.f, s2 = 0.f;
#pragma unroll
  for (int j = 0; j < 4; ++j) {
    s1 += v[j];
    s2 += v[j] * v[j];
  }
#pragma unroll
  for (int dd = 1; dd < 64; dd <<= 1) {
    s1 += __shfl_xor(s1, dd, 64);
    s2 += __shfl_xor(s2, dd, 64);
  }
  __shared__ float p1[4], p2[4];
  const int lane = tid & 63, wv = tid >> 6;
  if (lane == 0) {
    p1[wv] = s1;
    p2[wv] = s2;
  }
  __syncthreads();
  s1 = p1[0] + p1[1] + p1[2] + p1[3];
  s2 = p2[0] + p2[1] + p2[2] + p2[3];
  const float mu = s1 * (1.f / DM);
  const float rs = rsqrtf(fmaxf(s2 * (1.f / DM) - mu * mu, 0.f) + 1e-5f);
  float4 gg = *(const float4*)&g[tid * 4];
  float4 bb = *(const float4*)&be[tid * 4];
  const float gv[4] = {gg.x, gg.y, gg.z, gg.w};
  const float bv[4] = {bb.x, bb.y, bb.z, bb.w};
  uint2 o;
  u16* po = (u16*)&o;
#pragma unroll
  for (int j = 0; j < 4; ++j) po[j] = f2bf((v[j] - mu) * rs * gv[j] + bv[j]);
  *(uint2*)&y[(size_t)row * DM + tid * 4] = o;
}

// ---------------------------------------------------------------- GEMM
// C(M,N) = A(M,K)*Bt(N,K)^T + bias. A,Bt bf16; bias/resid fp32.
// Tile TM x 128, BK=64, XCD m-band swizzle, XOR-swizzled LDS layout.
// EPI: 0 plain->bf16, 1 +resid->fp32, 2 gelu->bf16,
//      3 qkv scatter WITH FUSED ROPE (q scaled by QSC; v transposed),
//      4 scaled scatter [B,H,SL,64], 5 scatter transposed [B,H,64,SL],
//      6 kc/vc pair: blockIdx.z=0 -> C0 as EPI4; z=1 -> Bt=C1,bias=resid,
//        output C2 as EPI5.
template <int EPI, int TM>
__global__ __launch_bounds__(256) void gemm_bt(
    const u16* __restrict__ A, const u16* __restrict__ Bt,
    const float* __restrict__ bias, const float* __restrict__ resid,
    void* __restrict__ C0, u16* __restrict__ C1, u16* __restrict__ C2, int M,
    int N, int K, int rpbl, float sc, const float* __restrict__ rcos,
    const float* __restrict__ rsin) {
  constexpr int MI = TM / 32;  // m-fragments per wave
  __shared__ __align__(16) u16 As[TM][64];
  __shared__ __align__(16) u16 Bs[128][64];
  const int tid = threadIdx.x;
  const int lane = tid & 63, wv = tid >> 6;
  const int l16 = lane & 15, quad = lane >> 4;

  if (EPI == 6 && blockIdx.z) {  // v-branch: swap weight/bias
    Bt = (const u16*)C1;
    bias = resid;
  }

  // XCD-aware m-band swizzle (n-fastest within band)
  int bx = blockIdx.x, by = blockIdx.y;
  const int gx = gridDim.x, gy = gridDim.y;
  if ((gy & 7) == 0) {
    const int f = by * gx + bx;
    const int c = f & 7, j = f >> 3;
    const int jm = j / gx;
    by = c * (gy >> 3) + jm;
    bx = j - jm * gx;
  }
  const int m0 = by * TM, n0 = bx * 128;
  const int wm = (wv >> 1) * (TM / 2), wn = (wv & 1) * 64;

  const int srow = lane >> 3;
  const int sblk = (lane & 7) ^ srow;
  const u16* ag[MI];
  const u16* bg[4];
  u16* la[MI];
  u16* lb[4];
#pragma unroll
  for (int i = 0; i < MI; ++i) {
    const int r0 = i * 32 + wv * 8;
    ag[i] = A + (size_t)(m0 + r0 + srow) * K + sblk * 8;
    la[i] = &As[r0][0] + lane * 8;
  }
#pragma unroll
  for (int i = 0; i < 4; ++i) {
    const int r0 = i * 32 + wv * 8;
    bg[i] = Bt + (size_t)(n0 + r0 + srow) * K + sblk * 8;
    lb[i] = &Bs[r0][0] + lane * 8;
  }

  f32x4 acc[MI][4] = {};

  for (int k0 = 0; k0 < K; k0 += 64) {
    __syncthreads();
#pragma unroll
    for (int i = 0; i < MI; ++i) load_lds16(ag[i] + k0, la[i]);
#pragma unroll
    for (int i = 0; i < 4; ++i) load_lds16(bg[i] + k0, lb[i]);
    __syncthreads();
#pragma unroll
    for (int kk = 0; kk < 2; ++kk) {
      bf16x8 af[MI], bfr[4];
#pragma unroll
      for (int mi = 0; mi < MI; ++mi) {
        const int row = wm + mi * 16 + l16;
        const int blk = (kk * 4 + quad) ^ (row & 7);
        af[mi] = *(const bf16x8*)&As[row][blk * 8];
      }
#pragma unroll
      for (int ni = 0; ni < 4; ++ni) {
        const int row = wn + ni * 16 + l16;
        const int blk = (kk * 4 + quad) ^ (row & 7);
        bfr[ni] = *(const bf16x8*)&Bs[row][blk * 8];
      }
#pragma unroll
      for (int mi = 0; mi < MI; ++mi)
#pragma unroll
        for (int ni = 0; ni < 4; ++ni)
          acc[mi][ni] = __builtin_amdgcn_mfma_f32_16x16x32_bf16(
              af[mi], bfr[ni], acc[mi][ni], 0, 0, 0);
    }
  }

  const int SL = 1 << rpbl;
#pragma unroll
  for (int mi = 0; mi < MI; ++mi) {
#pragma unroll
    for (int ni = 0; ni < 4; ++ni) {
#pragma unroll
      for (int r = 0; r < 4; ++r) {
        const int row = m0 + wm + mi * 16 + quad * 4 + r;
        const int col = n0 + wn + ni * 16 + l16;
        float vv = acc[mi][ni][r] + bias[col];
        if (EPI == 1) {
          vv += resid[(size_t)row * N + col];
          ((float*)C0)[(size_t)row * N + col] = vv;
        } else if (EPI == 2) {
          ((u16*)C0)[(size_t)row * N + col] = f2bf(geluf(vv));
        } else if (EPI == 3) {
          const float partner = __shfl_xor(vv, 1);
          const int which = col >> 10;
          const int nn = col & 1023;
          const int h = nn >> 6, hd = nn & 63;
          const int b = row >> rpbl;
          const int s = row & (SL - 1);
          if (which == 2) {  // V: transposed [B,H,64,SL]
            C2[(((size_t)b * HN + h) * SD + hd) * SL + s] = f2bf(vv);
          } else {  // q/k: fused RoPE
            const int p = hd >> 1;
            const float cv = rcos[s * 32 + p];
            const float sv2 = rsin[s * 32 + p];
            float o = (hd & 1) ? (partner * sv2 + vv * cv)
                               : (vv * cv - partner * sv2);
            if (which == 0) o *= QSC;
            u16* dst = (which == 0) ? (u16*)C0 : C1;
            dst[(((size_t)b * HN + h) * SL + s) * SD + hd] = f2bf(o);
          }
        } else if (EPI == 4) {
          vv *= sc;
          const int h = col >> 6, hd = col & 63;
          const int b = row >> rpbl;
          const int s = row & (SL - 1);
          ((u16*)C0)[(((size_t)b * HN + h) * SL + s) * SD + hd] = f2bf(vv);
        } else if (EPI == 5) {
          const int h = col >> 6, hd = col & 63;
          const int b = row >> rpbl;
          const int s = row & (SL - 1);
          ((u16*)C0)[(((size_t)b * HN + h) * SD + hd) * SL + s] = f2bf(vv);
        } else if (EPI == 6) {
          const int h = col >> 6, hd = col & 63;
          const int b = row >> rpbl;
          const int s = row & (SL - 1);
          if (blockIdx.z == 0)
            ((u16*)C0)[(((size_t)b * HN + h) * SL + s) * SD + hd] = f2bf(vv);
          else
            C2[(((size_t)b * HN + h) * SD + hd) * SL + s] = f2bf(vv);
        } else {
          ((u16*)C0)[(size_t)row * N + col] = f2bf(vv);
        }
      }
    }
  }
}

// ---------------------------------------------------------------- attention
// 8-wave dual-tile flash attention in exp2 domain (r7 scheme: work-balanced
// pairing). grid (16, B*H), 512 thr. Waves 0-3 own q-tile A (=bx), waves
// 4-7 own q-tile B (=31-bx causal, bx+16 cross); the two tile passes over a
// staged K/V tile run concurrently on disjoint waves.
// q: [B,H,2048,64]; k: [B,H,kv,64]; vt: [B,H,64,kv]. out: [B,S,1024] bf16.
template <int CAUSAL>
__global__ __launch_bounds__(512, 4) void attn_kernel(
    const u16* __restrict__ q, const u16* __restrict__ k,
    const u16* __restrict__ vt, u16* __restrict__ out, int kv_len) {
  __shared__ u16 Qs[128][72], Ks[64][72], VTs[64][72];
  __shared__ u16 Ps[128][68];  // wave-private rows [wv*16, wv*16+16)
  const int tid = threadIdx.x;
  const int lane = tid & 63, wv = tid >> 6;       // wave 0..7
  const int t2 = wv >> 2, w4 = wv & 3;            // tile group, strip in tile
  const int l16 = lane & 15, quad = lane >> 4;
  const int bx = blockIdx.x, bh = blockIdx.y;
  const int qtA = bx;
  const int qtB = CAUSAL ? (31 - bx) : (bx + 16);
  const int qt = t2 ? qtB : qtA;  // wave-uniform
  const u16* qb = q + (size_t)bh * SEQ * SD;
  const u16* kb = k + (size_t)bh * kv_len * SD;
  const u16* vtb = vt + (size_t)bh * SD * kv_len;

  // stage Q: rows 0..63 = tile A, 64..127 = tile B (2 x 16B per thread)
#pragma unroll
  for (int it = 0; it < 2; ++it) {
    const int t = it * 512 + tid, r = t >> 3, c = (t & 7) * 8;
    const int qrow = (r < 64) ? (qtA * 64 + r) : (qtB * 64 + (r - 64));
    *(uint4*)&Qs[r][c] = *(const uint4*)&qb[(size_t)qrow * SD + c];
  }

  f32x4 o_acc[4] = {};
  float l_i[4] = {};

  const int ktiles = CAUSAL ? (qtB + 1) : ((kv_len + 63) >> 6);
  const int sr = tid >> 3, sc8 = (tid & 7) * 8;  // staging row/col (1 ld/buf)

  for (int kt = 0; kt < ktiles; ++kt) {
    const uint4 kd = *(const uint4*)&kb[((size_t)kt * 64 + sr) * SD + sc8];
    const uint4 vd = *(const uint4*)&vtb[(size_t)sr * kv_len + kt * 64 + sc8];
    __syncthreads();
    *(uint4*)&Ks[sr][sc8] = kd;
    *(uint4*)&VTs[sr][sc8] = vd;
    __syncthreads();

    if (kt <= qt) {  // wave-uniform causal participation
      const int roff = t2 * 64 + w4 * 16;
      f32x4 s_acc[4] = {};
#pragma unroll
      for (int kk = 0; kk < 64; kk += 32) {
        const bf16x8 aq = *(const bf16x8*)&Qs[roff + l16][kk + quad * 8];
#pragma unroll
        for (int ni = 0; ni < 4; ++ni) {
          const bf16x8 bk = *(const bf16x8*)&Ks[ni * 16 + l16][kk + quad * 8];
          s_acc[ni] = __builtin_amdgcn_mfma_f32_16x16x32_bf16(aq, bk, s_acc[ni],
                                                              0, 0, 0);
        }
      }
      float rsum[4] = {0.f, 0.f, 0.f, 0.f};
      const bool dg = CAUSAL && (kt == qt);
#pragma unroll
      for (int ni = 0; ni < 4; ++ni)
#pragma unroll
        for (int r = 0; r < 4; ++r) {
          float sv = s_acc[ni][r];
          if (dg && (ni * 16 + l16 > w4 * 16 + quad * 4 + r)) sv = -1e9f;
          const float pe = __builtin_amdgcn_exp2f(sv);
          rsum[r] += pe;
          Ps[wv * 16 + quad * 4 + r][ni * 16 + l16] =
              (u16)(__float_as_uint(pe) >> 16);
        }
#pragma unroll
      for (int r = 0; r < 4; ++r) {
#pragma unroll
        for (int dd = 1; dd < 16; dd <<= 1)
          rsum[r] += __shfl_xor(rsum[r], dd, 64);
        l_i[r] += rsum[r];
      }
#pragma unroll
      for (int kk = 0; kk < 64; kk += 32) {
        const bf16x8 ap = *(const bf16x8*)&Ps[wv * 16 + l16][kk + quad * 8];
#pragma unroll
        for (int ni = 0; ni < 4; ++ni) {
          const bf16x8 bv = *(const bf16x8*)&VTs[ni * 16 + l16][kk + quad * 8];
          o_acc[ni] = __builtin_amdgcn_mfma_f32_16x16x32_bf16(ap, bv, o_acc[ni],
                                                              0, 0, 0);
        }
      }
    }
  }

  const int b = bh >> 4, h = bh & 15;
#pragma unroll
  for (int r = 0; r < 4; ++r) {
    const float inv = 1.f / l_i[r];
    const int s = qt * 64 + w4 * 16 + quad * 4 + r;
#pragma unroll
    for (int ni = 0; ni < 4; ++ni)
      out[((size_t)b * SEQ + s) * DM + h * SD + ni * 16 + l16] =
          f2bf(o_acc[ni][r] * inv);
  }
}

// ---------------------------------------------------------------- launch
extern "C" void kernel_launch(void* const* d_in, const int* in_sizes, int n_in,
                              void* d_out, int out_size, void* d_ws,
                              size_t ws_size, hipStream_t stream) {
  (void)in_sizes;
  (void)n_in;
  (void)out_size;
  (void)ws_size;
  const float* tgt = (const float*)d_in[0];
  const float* mem = (const float*)d_in[1];
  const float* rc = (const float*)d_in[2];
  const float* rsn = (const float*)d_in[3];
  const float* W_qkv = (const float*)d_in[4];
  const float* b_qkv = (const float*)d_in[5];
  const float* W_o = (const float*)d_in[6];
  const float* b_o = (const float*)d_in[7];
  const float* Wq_c = (const float*)d_in[8];
  const float* bq_c = (const float*)d_in[9];
  const float* Wk_c = (const float*)d_in[10];
  const float* bk_c = (const float*)d_in[11];
  const float* Wv_c = (const float*)d_in[12];
  const float* bv_c = (const float*)d_in[13];
  const float* W_co = (const float*)d_in[14];
  const float* b_co = (const float*)d_in[15];
  const float* W1 = (const float*)d_in[16];
  const float* b1 = (const float*)d_in[17];
  const float* W2 = (const float*)d_in[18];
  const float* b2 = (const float*)d_in[19];
  const float* g1 = (const float*)d_in[20];
  const float* be1 = (const float*)d_in[21];
  const float* g2 = (const float*)d_in[22];
  const float* be2 = (const float*)d_in[23];
  const float* g3 = (const float*)d_in[24];
  const float* be3 = (const float*)d_in[25];

  // --- workspace layout (u16 elements), ~57 MB ---
  const size_t M1 = 1048576;
  u16* w = (u16*)d_ws;
  u16* WTqkv = w;          // 3M  } early-WT region: 8M u16, dead after W_co
  u16* WTo = w + 3 * M1;   // 1M  } projection; reused for WT1/WT2
  u16* WTqc = w + 4 * M1;  // 1M
  u16* WTkc = w + 5 * M1;  // 1M
  u16* WTvc = w + 6 * M1;  // 1M
  u16* WTco = w + 7 * M1;  // 1M
  u16* WT1 = w;            // 4M (aliases WTqkv+WTo, transposed late)
  u16* WT2 = w + 4 * M1;   // 4M (aliases WTqc..WTco, transposed late)
  u16* xb = w + 8 * M1;    // 4M
  u16* qb = w + 12 * M1;   // 4M
  u16* kb = w + 16 * M1;   // 4M
  u16* vbT = w + 20 * M1;  // 4M  V pre-transposed [B,H,64,2048]
  u16* at = w + 24 * M1;   // 4M
  u16* kc = w + 28 * M1;   // 128K [B,H,64,64]
  u16* vcT = kc + 131072;  // 128K [B,H,64,64] transposed
  u16* memb = vcT + 131072;  // 128K memory as bf16
  u16* ffh = qb;             // FFN hidden 16M u16: aliases dead qb..at
  float* res = (float*)d_out;  // fp32 residual stream lives in d_out

  dim3 blk(256), blk512(512);
  prep1<<<2176, blk, 0, stream>>>(W_qkv, W_o, Wq_c, Wk_c, Wv_c, W_co, WTqkv,
                                  WTo, WTqc, WTkc, WTvc, WTco, mem, memb);

  // --- self-attention block
  ln_kernel<<<4096, blk, 0, stream>>>(tgt, g1, be1, xb);
  gemm_bt<3, 128><<<dim3(24, 32), blk, 0, stream>>>(
      xb, WTqkv, b_qkv, nullptr, qb, kb, vbT, 4096, 3072, 1024, 11, 1.f, rc,
      rsn);
  attn_kernel<1><<<dim3(16, 32), blk512, 0, stream>>>(qb, kb, vbT, at, 2048);
  gemm_bt<1, 64><<<dim3(8, 64), blk, 0, stream>>>(at, WTo, b_o, tgt, res,
                                                  nullptr, nullptr, 4096, 1024,
                                                  1024, 0, 1.f, nullptr,
                                                  nullptr);
  // --- cross-attention block
  ln_kernel<<<4096, blk, 0, stream>>>(res, g2, be2, xb);
  gemm_bt<4, 64><<<dim3(8, 64), blk, 0, stream>>>(
      xb, WTqc, bq_c, nullptr, qb, nullptr, nullptr, 4096, 1024, 1024, 11, QSC,
      nullptr, nullptr);
  gemm_bt<6, 64><<<dim3(8, 2, 2), blk, 0, stream>>>(
      memb, WTkc, bk_c, bv_c, kc, WTvc, vcT, 128, 1024, 1024, 6, 1.f, nullptr,
      nullptr);
  attn_kernel<0><<<dim3(16, 32), blk512, 0, stream>>>(qb, kc, vcT, at, 64);
  gemm_bt<1, 64><<<dim3(8, 64), blk, 0, stream>>>(at, WTco, b_co, res, res,
                                                  nullptr, nullptr, 4096, 1024,
                                                  1024, 0, 1.f, nullptr,
                                                  nullptr);
  // --- FFN block (early WTs now dead; transpose W1/W2 into their region)
  prep2<<<2048, blk, 0, stream>>>(W1, W2, WT1, WT2);
  ln_kernel<<<4096, blk, 0, stream>>>(res, g3, be3, xb);
  gemm_bt<2, 128><<<dim3(32, 32), blk, 0, stream>>>(
      xb, WT1, b1, nullptr, ffh, nullptr, nullptr, 4096, 4096, 1024, 0, 1.f,
      nullptr, nullptr);
  gemm_bt<1, 64><<<dim3(8, 64), blk, 0, stream>>>(ffh, WT2, b2, res, res,
                                                  nullptr, nullptr, 4096, 1024,
                                                  4096, 0, 1.f, nullptr,
                                                  nullptr);
}